// Round 6
// baseline (235.835 us; speedup 1.0000x reference)
//
#include <hip/hip_runtime.h>

// LogicGatedSNN fused kernel, v6: one wave per output row, zero barriers,
// SHALLOW chunks (4 x float4) + __launch_bounds__(256,8) to keep VGPR <= 64
// so 8 waves/SIMD stay resident (v5's CHUNK=8 hit VGPR=124 -> 20% occupancy).
// Cached loads (L3 serves the syn matrix, exactly 256 MiB), NT stores only.
// Outputs concatenated in d_out (all float32):
//   [0, 8192)                 spikes
//   [8192, 16384)             new_v_mem
//   [16384, 16384+8192*8192)  new_trace (row-major [out][in])

#define IN_F 8192
#define OUT_F 8192
#define THR_F 50.0f
#define BLOCK 256          // 4 waves -> 4 rows per block
#define WAVES_PER_BLOCK 4
// per row: 8192/4 = 2048 f4; per lane: 2048/64 = 32 f4; 8 chunks of 4
#define CHUNK 4
#define NCHUNK 8

typedef float f4 __attribute__((ext_vector_type(4)));

__global__ __launch_bounds__(BLOCK, 8) void snn_wave_kernel(
    const float* __restrict__ x,        // [IN_F]
    const float* __restrict__ syn,      // [OUT_F * IN_F]
    const float* __restrict__ vmem_in,  // [OUT_F]
    const float* __restrict__ thr,      // [OUT_F]
    const float* __restrict__ trace_in, // [OUT_F * IN_F]
    float* __restrict__ out_spikes,     // [OUT_F]
    float* __restrict__ out_vmem,       // [OUT_F]
    float* __restrict__ out_trace)      // [OUT_F * IN_F]
{
    const int wid  = threadIdx.x >> 6;
    const int lane = threadIdx.x & 63;
    const int o    = blockIdx.x * WAVES_PER_BLOCK + wid;
    const size_t rowoff = (size_t)o * IN_F;

    const f4* __restrict__ syn4 = reinterpret_cast<const f4*>(syn + rowoff);
    const f4* __restrict__ x4   = reinterpret_cast<const f4*>(x);
    const f4* __restrict__ tr4  = reinterpret_cast<const f4*>(trace_in + rowoff);
    f4* __restrict__ ot4        = reinterpret_cast<f4*>(out_trace + rowoff);

    // ---- Phase 1: row dot, 8 chunks of 4 f4 per lane (8 loads in flight) ----
    float partial = 0.0f;
#pragma unroll
    for (int c = 0; c < NCHUNK; ++c) {
        f4 s[CHUNK], xv[CHUNK];
#pragma unroll
        for (int j = 0; j < CHUNK; ++j) {
            const int idx = lane + (c * CHUNK + j) * 64;
            s[j]  = syn4[idx];
            xv[j] = x4[idx];
        }
#pragma unroll
        for (int j = 0; j < CHUNK; ++j) {
            partial += (s[j].x > THR_F) ? xv[j].x : 0.0f;
            partial += (s[j].y > THR_F) ? xv[j].y : 0.0f;
            partial += (s[j].z > THR_F) ? xv[j].z : 0.0f;
            partial += (s[j].w > THR_F) ? xv[j].w : 0.0f;
        }
    }

    // ---- Wave-64 butterfly reduce: ALL lanes end with the total ----
#pragma unroll
    for (int off = 32; off > 0; off >>= 1)
        partial += __shfl_xor(partial, off, 64);

    // ---- LIF update, uniform across the wave (no divergence, no bcast) ----
    const float v  = vmem_in[o] * 0.7f + partial;
    const float sp = (v >= thr[o]) ? 1.0f : 0.0f;
    if (lane == 0) {
        out_spikes[o] = sp;
        out_vmem[o]   = v * (1.0f - sp) * 0.5f;
    }

    // ---- Phase 2: trace update, 8 chunks of 4 f4, NT stores ----
#pragma unroll
    for (int c = 0; c < NCHUNK; ++c) {
        f4 t[CHUNK], xv[CHUNK];
#pragma unroll
        for (int j = 0; j < CHUNK; ++j) {
            const int idx = lane + (c * CHUNK + j) * 64;
            t[j]  = tr4[idx];
            xv[j] = x4[idx];
        }
#pragma unroll
        for (int j = 0; j < CHUNK; ++j) {
            const int idx = lane + (c * CHUNK + j) * 64;
            f4 r;
            r.x = t[j].x * 0.8f + sp * xv[j].x;
            r.y = t[j].y * 0.8f + sp * xv[j].y;
            r.z = t[j].z * 0.8f + sp * xv[j].z;
            r.w = t[j].w * 0.8f + sp * xv[j].w;
            __builtin_nontemporal_store(r, &ot4[idx]);
        }
    }
}

extern "C" void kernel_launch(void* const* d_in, const int* in_sizes, int n_in,
                              void* d_out, int out_size, void* d_ws, size_t ws_size,
                              hipStream_t stream) {
    const float* x     = (const float*)d_in[0]; // spike_input [1,8192]
    const float* syn   = (const float*)d_in[1]; // synapse_states [8192,8192]
    const float* vmem  = (const float*)d_in[2]; // membrane_potential [8192]
    const float* thr   = (const float*)d_in[3]; // adaptive_threshold [8192]
    const float* trace = (const float*)d_in[4]; // eligibility_trace [8192,8192]

    float* out = (float*)d_out;
    float* out_spikes = out;             // [8192]
    float* out_vmem   = out + OUT_F;     // [8192]
    float* out_trace  = out + 2 * OUT_F; // [8192*8192]

    snn_wave_kernel<<<OUT_F / WAVES_PER_BLOCK, BLOCK, 0, stream>>>(
        x, syn, vmem, thr, trace, out_spikes, out_vmem, out_trace);
}

// Round 7
// 165.785 us; speedup vs baseline: 1.4225x; 1.4225x over previous
//
#include <hip/hip_runtime.h>

// LogicGatedSNN fused kernel, v7: clean wave-per-row test.
// - one wave per output row, ZERO barriers
// - CHUNK=4 f4 live set (~32 regs) -> no spill; launch_bounds(256,4) is a
//   generous cap (128 VGPR), NOT a spill-forcing bound (v6's mistake)
// - cached loads (L3 serves syn), nontemporal STORES only (v4's NT-load
//   regression avoided)
// Outputs concatenated in d_out (all float32):
//   [0, 8192)                 spikes
//   [8192, 16384)             new_v_mem
//   [16384, 16384+8192*8192)  new_trace (row-major [out][in])

#define IN_F 8192
#define OUT_F 8192
#define THR_F 50.0f
#define BLOCK 256          // 4 waves -> 4 rows per block
#define WAVES_PER_BLOCK 4
// per row: 8192/4 = 2048 f4; per lane: 2048/64 = 32 f4; 8 chunks of 4
#define CHUNK 4
#define NCHUNK 8

typedef float f4 __attribute__((ext_vector_type(4)));

__global__ __launch_bounds__(BLOCK, 4) void snn_wave_kernel(
    const float* __restrict__ x,        // [IN_F]
    const float* __restrict__ syn,      // [OUT_F * IN_F]
    const float* __restrict__ vmem_in,  // [OUT_F]
    const float* __restrict__ thr,      // [OUT_F]
    const float* __restrict__ trace_in, // [OUT_F * IN_F]
    float* __restrict__ out_spikes,     // [OUT_F]
    float* __restrict__ out_vmem,       // [OUT_F]
    float* __restrict__ out_trace)      // [OUT_F * IN_F]
{
    const int wid  = threadIdx.x >> 6;
    const int lane = threadIdx.x & 63;
    const int o    = blockIdx.x * WAVES_PER_BLOCK + wid;
    const size_t rowoff = (size_t)o * IN_F;

    const f4* __restrict__ syn4 = reinterpret_cast<const f4*>(syn + rowoff);
    const f4* __restrict__ x4   = reinterpret_cast<const f4*>(x);
    const f4* __restrict__ tr4  = reinterpret_cast<const f4*>(trace_in + rowoff);
    f4* __restrict__ ot4        = reinterpret_cast<f4*>(out_trace + rowoff);

    // ---- Phase 1: row dot, 8 chunks of 4 f4 per lane ----
    float p0 = 0.0f, p1 = 0.0f;
#pragma unroll
    for (int c = 0; c < NCHUNK; ++c) {
        f4 s[CHUNK], xv[CHUNK];
#pragma unroll
        for (int j = 0; j < CHUNK; ++j) {
            const int idx = lane + (c * CHUNK + j) * 64;
            s[j]  = syn4[idx];
            xv[j] = x4[idx];
        }
#pragma unroll
        for (int j = 0; j < CHUNK; ++j) {
            p0 += (s[j].x > THR_F) ? xv[j].x : 0.0f;
            p1 += (s[j].y > THR_F) ? xv[j].y : 0.0f;
            p0 += (s[j].z > THR_F) ? xv[j].z : 0.0f;
            p1 += (s[j].w > THR_F) ? xv[j].w : 0.0f;
        }
    }
    float partial = p0 + p1;

    // ---- Wave-64 butterfly reduce: ALL lanes end with the total ----
#pragma unroll
    for (int off = 32; off > 0; off >>= 1)
        partial += __shfl_xor(partial, off, 64);

    // ---- LIF update, uniform across the wave ----
    const float v  = vmem_in[o] * 0.7f + partial;
    const float sp = (v >= thr[o]) ? 1.0f : 0.0f;
    if (lane == 0) {
        out_spikes[o] = sp;
        out_vmem[o]   = v * (1.0f - sp) * 0.5f;
    }

    // ---- Phase 2: trace update, 8 chunks of 4 f4, NT stores ----
#pragma unroll
    for (int c = 0; c < NCHUNK; ++c) {
        f4 t[CHUNK], xv[CHUNK];
#pragma unroll
        for (int j = 0; j < CHUNK; ++j) {
            const int idx = lane + (c * CHUNK + j) * 64;
            t[j]  = tr4[idx];
            xv[j] = x4[idx];
        }
#pragma unroll
        for (int j = 0; j < CHUNK; ++j) {
            const int idx = lane + (c * CHUNK + j) * 64;
            f4 r;
            r.x = t[j].x * 0.8f + sp * xv[j].x;
            r.y = t[j].y * 0.8f + sp * xv[j].y;
            r.z = t[j].z * 0.8f + sp * xv[j].z;
            r.w = t[j].w * 0.8f + sp * xv[j].w;
            __builtin_nontemporal_store(r, &ot4[idx]);
        }
    }
}

extern "C" void kernel_launch(void* const* d_in, const int* in_sizes, int n_in,
                              void* d_out, int out_size, void* d_ws, size_t ws_size,
                              hipStream_t stream) {
    const float* x     = (const float*)d_in[0]; // spike_input [1,8192]
    const float* syn   = (const float*)d_in[1]; // synapse_states [8192,8192]
    const float* vmem  = (const float*)d_in[2]; // membrane_potential [8192]
    const float* thr   = (const float*)d_in[3]; // adaptive_threshold [8192]
    const float* trace = (const float*)d_in[4]; // eligibility_trace [8192,8192]

    float* out = (float*)d_out;
    float* out_spikes = out;             // [8192]
    float* out_vmem   = out + OUT_F;     // [8192]
    float* out_trace  = out + 2 * OUT_F; // [8192*8192]

    snn_wave_kernel<<<OUT_F / WAVES_PER_BLOCK, BLOCK, 0, stream>>>(
        x, syn, vmem, thr, trace, out_spikes, out_vmem, out_trace);
}

// Round 8
// 155.334 us; speedup vs baseline: 1.5182x; 1.0673x over previous
//
#include <hip/hip_runtime.h>

// LogicGatedSNN fused kernel, v8: block-per-row-group with cross-row
// software pipeline. Step r overlaps {dot of row r} with {trace update of
// row r-1}, so syn-read and trace-read/write streams hit DRAM concurrently
// instead of alternating as global phases (v2b's limiter).
// One barrier per row, double-buffered LDS partials.
// Outputs concatenated in d_out (all float32):
//   [0, 8192)                 spikes
//   [8192, 16384)             new_v_mem
//   [16384, 16384+8192*8192)  new_trace (row-major [out][in])

#define IN_F 8192
#define OUT_F 8192
#define THR_F 50.0f
#define BLOCK 256
#define RPB 4            // rows per block
#define NCHUNK 8         // (8192/4) f4 per row / 256 threads = 8

typedef float f4 __attribute__((ext_vector_type(4)));

__global__ __launch_bounds__(BLOCK) void snn_pipe_kernel(
    const float* __restrict__ x,        // [IN_F]
    const float* __restrict__ syn,      // [OUT_F * IN_F]
    const float* __restrict__ vmem_in,  // [OUT_F]
    const float* __restrict__ thr,      // [OUT_F]
    const float* __restrict__ trace_in, // [OUT_F * IN_F]
    float* __restrict__ out_spikes,     // [OUT_F]
    float* __restrict__ out_vmem,       // [OUT_F]
    float* __restrict__ out_trace)      // [OUT_F * IN_F]
{
    const int tid  = threadIdx.x;
    const int base = blockIdx.x * RPB;
    const f4* __restrict__ x4 = reinterpret_cast<const f4*>(x);

    __shared__ float wsum[2][4];   // double-buffered per-wave partials

    float sp_prev = 0.0f;          // spike of row base+r-1 (uniform)

#pragma unroll
    for (int r = 0; r <= RPB; ++r) {
        const bool do_dot = (r < RPB);
        const bool do_tr  = (r > 0);
        const int  dot_row = base + (do_dot ? r : 0);
        const int  tr_row  = base + (do_tr ? (r - 1) : 0);

        const f4* __restrict__ syn4 =
            reinterpret_cast<const f4*>(syn + (size_t)dot_row * IN_F);
        const f4* __restrict__ tr4 =
            reinterpret_cast<const f4*>(trace_in + (size_t)tr_row * IN_F);
        f4* __restrict__ ot4 =
            reinterpret_cast<f4*>(out_trace + (size_t)tr_row * IN_F);

        float partial = 0.0f;
#pragma unroll
        for (int c = 0; c < NCHUNK; ++c) {
            const int idx = tid + c * BLOCK;
            const f4 xv = x4[idx];              // L1-resident (32 KB)
            if (do_dot) {
                const f4 s = syn4[idx];
                partial += (s.x > THR_F) ? xv.x : 0.0f;
                partial += (s.y > THR_F) ? xv.y : 0.0f;
                partial += (s.z > THR_F) ? xv.z : 0.0f;
                partial += (s.w > THR_F) ? xv.w : 0.0f;
            }
            if (do_tr) {
                const f4 t = tr4[idx];
                f4 res;
                res.x = t.x * 0.8f + sp_prev * xv.x;
                res.y = t.y * 0.8f + sp_prev * xv.y;
                res.z = t.z * 0.8f + sp_prev * xv.z;
                res.w = t.w * 0.8f + sp_prev * xv.w;
                __builtin_nontemporal_store(res, &ot4[idx]);
            }
        }

        if (do_dot) {
            // wave-64 butterfly: all lanes end with the wave total
#pragma unroll
            for (int off = 32; off > 0; off >>= 1)
                partial += __shfl_xor(partial, off, 64);
            if ((tid & 63) == 0) wsum[r & 1][tid >> 6] = partial;
            __syncthreads();
            // every thread computes the spike uniformly (no 2nd barrier;
            // wsum is double-buffered so next row's writes don't race)
            const float cur = wsum[r & 1][0] + wsum[r & 1][1] +
                              wsum[r & 1][2] + wsum[r & 1][3];
            const float v  = vmem_in[dot_row] * 0.7f + cur;
            const float sp = (v >= thr[dot_row]) ? 1.0f : 0.0f;
            if (tid == 0) {
                out_spikes[dot_row] = sp;
                out_vmem[dot_row]   = v * (1.0f - sp) * 0.5f;
            }
            sp_prev = sp;
        }
    }
}

extern "C" void kernel_launch(void* const* d_in, const int* in_sizes, int n_in,
                              void* d_out, int out_size, void* d_ws, size_t ws_size,
                              hipStream_t stream) {
    const float* x     = (const float*)d_in[0]; // spike_input [1,8192]
    const float* syn   = (const float*)d_in[1]; // synapse_states [8192,8192]
    const float* vmem  = (const float*)d_in[2]; // membrane_potential [8192]
    const float* thr   = (const float*)d_in[3]; // adaptive_threshold [8192]
    const float* trace = (const float*)d_in[4]; // eligibility_trace [8192,8192]

    float* out = (float*)d_out;
    float* out_spikes = out;             // [8192]
    float* out_vmem   = out + OUT_F;     // [8192]
    float* out_trace  = out + 2 * OUT_F; // [8192*8192]

    snn_pipe_kernel<<<OUT_F / RPB, BLOCK, 0, stream>>>(
        x, syn, vmem, thr, trace, out_spikes, out_vmem, out_trace);
}

// Round 9
// 139.772 us; speedup vs baseline: 1.6873x; 1.1113x over previous
//
#include <hip/hip_runtime.h>

// LogicGatedSNN fused kernel, v9 = v2b (the 119 µs champion) + two local
// trims: single barrier (all threads compute the spike uniformly from the
// 4 wave partials; no s_spike broadcast), and early scalar loads of the
// per-row LIF params. Structure: block per row, phase 1 dot (syn from L3,
// x from L1), trace row preloaded to registers up front, phase 2 FMA +
// nontemporal stores.
// Outputs concatenated in d_out (all float32):
//   [0, 8192)                 spikes
//   [8192, 16384)             new_v_mem
//   [16384, 16384+8192*8192)  new_trace (row-major [out][in])

#define IN_F 8192
#define OUT_F 8192
#define THR_F 50.0f
#define BLOCK 256
// float4 elements per row = 8192/4 = 2048; per-thread = 2048/256 = 8
#define V4_PER_THREAD 8

typedef float f4 __attribute__((ext_vector_type(4)));

__global__ __launch_bounds__(BLOCK) void snn_fused_kernel(
    const float* __restrict__ x,        // [IN_F]
    const float* __restrict__ syn,      // [OUT_F * IN_F]
    const float* __restrict__ vmem_in,  // [OUT_F]
    const float* __restrict__ thr,      // [OUT_F]
    const float* __restrict__ trace_in, // [OUT_F * IN_F]
    float* __restrict__ out_spikes,     // [OUT_F]
    float* __restrict__ out_vmem,       // [OUT_F]
    float* __restrict__ out_trace)      // [OUT_F * IN_F]
{
    const int o = blockIdx.x;
    const int tid = threadIdx.x;
    const size_t rowoff = (size_t)o * IN_F;

    // Per-row LIF params: wave-uniform, issue early (scalar loads).
    const float vm = vmem_in[o];
    const float th = thr[o];

    const f4* __restrict__ syn4 = reinterpret_cast<const f4*>(syn + rowoff);
    const f4* __restrict__ x4   = reinterpret_cast<const f4*>(x);
    const f4* __restrict__ tr4  = reinterpret_cast<const f4*>(trace_in + rowoff);
    f4* __restrict__ ot4        = reinterpret_cast<f4*>(out_trace + rowoff);

    // ---- Trace row -> registers up front; latency hides under the dot ----
    f4 tr[V4_PER_THREAD];
#pragma unroll
    for (int j = 0; j < V4_PER_THREAD; ++j)
        tr[j] = tr4[tid + j * BLOCK];

    // ---- Phase 1: row dot ----
    float partial = 0.0f;
#pragma unroll
    for (int j = 0; j < V4_PER_THREAD; ++j) {
        const int idx = tid + j * BLOCK;
        const f4 s  = syn4[idx];
        const f4 xv = x4[idx];
        partial += (s.x > THR_F) ? xv.x : 0.0f;
        partial += (s.y > THR_F) ? xv.y : 0.0f;
        partial += (s.z > THR_F) ? xv.z : 0.0f;
        partial += (s.w > THR_F) ? xv.w : 0.0f;
    }

    // wave-64 butterfly: all lanes end with their wave's total
#pragma unroll
    for (int off = 32; off > 0; off >>= 1)
        partial += __shfl_xor(partial, off, 64);

    __shared__ float wsum[BLOCK / 64];
    if ((tid & 63) == 0) wsum[tid >> 6] = partial;
    __syncthreads();

    // Every thread computes the spike uniformly — no 2nd barrier/broadcast.
    const float cur = wsum[0] + wsum[1] + wsum[2] + wsum[3];
    const float v   = vm * 0.7f + cur;
    const float sp  = (v >= th) ? 1.0f : 0.0f;
    if (tid == 0) {
        out_spikes[o] = sp;
        out_vmem[o]   = v * (1.0f - sp) * 0.5f;
    }

    // ---- Phase 2: trace update from registers, NT streaming stores ----
#pragma unroll
    for (int j = 0; j < V4_PER_THREAD; ++j) {
        const int idx = tid + j * BLOCK;
        const f4 xv = x4[idx];   // L1 hit
        f4 r;
        r.x = tr[j].x * 0.8f + sp * xv.x;
        r.y = tr[j].y * 0.8f + sp * xv.y;
        r.z = tr[j].z * 0.8f + sp * xv.z;
        r.w = tr[j].w * 0.8f + sp * xv.w;
        __builtin_nontemporal_store(r, &ot4[idx]);
    }
}

extern "C" void kernel_launch(void* const* d_in, const int* in_sizes, int n_in,
                              void* d_out, int out_size, void* d_ws, size_t ws_size,
                              hipStream_t stream) {
    const float* x     = (const float*)d_in[0]; // spike_input [1,8192]
    const float* syn   = (const float*)d_in[1]; // synapse_states [8192,8192]
    const float* vmem  = (const float*)d_in[2]; // membrane_potential [8192]
    const float* thr   = (const float*)d_in[3]; // adaptive_threshold [8192]
    const float* trace = (const float*)d_in[4]; // eligibility_trace [8192,8192]

    float* out = (float*)d_out;
    float* out_spikes = out;             // [8192]
    float* out_vmem   = out + OUT_F;     // [8192]
    float* out_trace  = out + 2 * OUT_F; // [8192*8192]

    snn_fused_kernel<<<OUT_F, BLOCK, 0, stream>>>(
        x, syn, vmem, thr, trace, out_spikes, out_vmem, out_trace);
}

// Round 10
// 118.891 us; speedup vs baseline: 1.9836x; 1.1756x over previous
//
#include <hip/hip_runtime.h>

// LogicGatedSNN fused kernel, v2b verbatim (the 119.1 µs champion) —
// reproduction test. Block per row; trace row preloaded via NONTEMPORAL
// loads up front (latency hides under the dot; nt keeps trace from
// competing with syn for cache retention); dot from cached loads (L3
// serves syn); two barriers + s_spike broadcast; NT streaming stores.
// Outputs concatenated in d_out (all float32):
//   [0, 8192)                 spikes
//   [8192, 16384)             new_v_mem
//   [16384, 16384+8192*8192)  new_trace (row-major [out][in])

#define IN_F 8192
#define OUT_F 8192
#define THR_F 50.0f
#define BLOCK 256
// float4 elements per row = 8192/4 = 2048; per-thread = 2048/256 = 8
#define V4_PER_THREAD 8

typedef float f4 __attribute__((ext_vector_type(4)));

__global__ __launch_bounds__(BLOCK) void snn_fused_kernel(
    const float* __restrict__ x,        // [IN_F] spike_input (flattened)
    const float* __restrict__ syn,      // [OUT_F * IN_F]
    const float* __restrict__ vmem_in,  // [OUT_F]
    const float* __restrict__ thr,      // [OUT_F]
    const float* __restrict__ trace_in, // [OUT_F * IN_F]
    float* __restrict__ out_spikes,     // [OUT_F]
    float* __restrict__ out_vmem,       // [OUT_F]
    float* __restrict__ out_trace)      // [OUT_F * IN_F]
{
    const int o = blockIdx.x;
    const int tid = threadIdx.x;
    const size_t rowoff = (size_t)o * IN_F;

    const f4* __restrict__ syn4 = reinterpret_cast<const f4*>(syn + rowoff);
    const f4* __restrict__ x4   = reinterpret_cast<const f4*>(x);
    const f4* __restrict__ tr4  = reinterpret_cast<const f4*>(trace_in + rowoff);
    f4* __restrict__ ot4        = reinterpret_cast<f4*>(out_trace + rowoff);

    // ---- Issue ALL loads up front: trace row -> registers (needed only
    // after the barrier), syn+x -> dot product. ----
    f4 tr[V4_PER_THREAD];
#pragma unroll
    for (int j = 0; j < V4_PER_THREAD; ++j) {
        const int idx = tid + j * BLOCK;
        tr[j] = __builtin_nontemporal_load(&tr4[idx]);
    }

    float partial = 0.0f;
#pragma unroll
    for (int j = 0; j < V4_PER_THREAD; ++j) {
        const int idx = tid + j * BLOCK;
        const f4 s  = syn4[idx];
        const f4 xv = x4[idx];
        partial += (s.x > THR_F) ? xv.x : 0.0f;
        partial += (s.y > THR_F) ? xv.y : 0.0f;
        partial += (s.z > THR_F) ? xv.z : 0.0f;
        partial += (s.w > THR_F) ? xv.w : 0.0f;
    }

    // wave-64 butterfly reduce
#pragma unroll
    for (int off = 32; off > 0; off >>= 1)
        partial += __shfl_down(partial, off, 64);

    __shared__ float wsum[BLOCK / 64];
    __shared__ float s_spike;
    const int wid = tid >> 6;
    const int lane = tid & 63;
    if (lane == 0) wsum[wid] = partial;
    __syncthreads();

    if (tid == 0) {
        const float cur = wsum[0] + wsum[1] + wsum[2] + wsum[3];
        const float v = vmem_in[o] * 0.7f + cur;
        const float sp = (v >= thr[o]) ? 1.0f : 0.0f;
        out_spikes[o] = sp;
        out_vmem[o] = v * (1.0f - sp) * 0.5f;
        s_spike = sp;
    }
    __syncthreads();
    const float sp = s_spike;

    // ---- Trace update: FMA on register-held trace + x (L1-hit reload),
    // nontemporal streaming stores. ----
#pragma unroll
    for (int j = 0; j < V4_PER_THREAD; ++j) {
        const int idx = tid + j * BLOCK;
        const f4 xv = x4[idx];
        f4 r;
        r.x = tr[j].x * 0.8f + sp * xv.x;
        r.y = tr[j].y * 0.8f + sp * xv.y;
        r.z = tr[j].z * 0.8f + sp * xv.z;
        r.w = tr[j].w * 0.8f + sp * xv.w;
        __builtin_nontemporal_store(r, &ot4[idx]);
    }
}

extern "C" void kernel_launch(void* const* d_in, const int* in_sizes, int n_in,
                              void* d_out, int out_size, void* d_ws, size_t ws_size,
                              hipStream_t stream) {
    const float* x     = (const float*)d_in[0]; // spike_input [1,8192]
    const float* syn   = (const float*)d_in[1]; // synapse_states [8192,8192]
    const float* vmem  = (const float*)d_in[2]; // membrane_potential [8192]
    const float* thr   = (const float*)d_in[3]; // adaptive_threshold [8192]
    const float* trace = (const float*)d_in[4]; // eligibility_trace [8192,8192]

    float* out = (float*)d_out;
    float* out_spikes = out;             // [8192]
    float* out_vmem   = out + OUT_F;     // [8192]
    float* out_trace  = out + 2 * OUT_F; // [8192*8192]

    snn_fused_kernel<<<OUT_F, BLOCK, 0, stream>>>(
        x, syn, vmem, thr, trace, out_spikes, out_vmem, out_trace);
}